// Round 6
// baseline (6283.310 us; speedup 1.0000x reference)
//
#include <hip/hip_runtime.h>
#include <hip/hip_bf16.h>

typedef __bf16 bf16_t;
typedef bf16_t bf16x8 __attribute__((ext_vector_type(8)));
typedef float  f32x4  __attribute__((ext_vector_type(4)));

constexpr int Bb = 64;
constexpr int T  = 512;
constexpr int D  = 512;
constexpr int H  = 512;
constexpr int M1 = Bb * T;     // 32768 rows of zi
constexpr int N1 = 3 * H;      // 1536 gate columns

#define LDK 72   // padded LDS row stride (bf16 elems)

// ---------------------------------------------------------------------------
// Phase 1: zi[dir] = x @ w_ih[dir]^T + b_ih   (fp32 in, bf16 MFMA, ZT out)
// 128x128 tile, BK=64, 4 waves each 64x64 via 16x16x32 bf16 MFMA. (unchanged)
// ---------------------------------------------------------------------------
template <typename ZT>
__global__ __launch_bounds__(256) void zi_gemm(
    const float* __restrict__ x,
    const float* __restrict__ w_fw, const float* __restrict__ w_bw,
    const float* __restrict__ b_fw, const float* __restrict__ b_bw,
    ZT* __restrict__ zi)
{
    const int dir = blockIdx.z;
    const float* __restrict__ w    = dir ? w_bw : w_fw;
    const float* __restrict__ bias = dir ? b_bw : b_fw;
    ZT* __restrict__ out = zi + (size_t)dir * M1 * N1;

    const int m0 = blockIdx.x * 128;
    const int n0 = blockIdx.y * 128;

    __shared__ bf16_t As[128 * LDK];
    __shared__ bf16_t Bs[128 * LDK];

    const int tid  = threadIdx.x;
    const int lane = tid & 63;
    const int wave = tid >> 6;
    const int wm = (wave >> 1) * 64;
    const int wn = (wave & 1) * 64;
    const int q   = lane >> 4;
    const int l16 = lane & 15;

    f32x4 acc[4][4] = {};

    for (int kt = 0; kt < D; kt += 64) {
#pragma unroll
        for (int p = 0; p < 4; ++p) {
            int idx = tid + p * 256;
            int row = idx >> 3;
            int seg = idx & 7;
            const float* sa = &x[(size_t)(m0 + row) * D + kt + seg * 8];
            const float* sb = &w[(size_t)(n0 + row) * D + kt + seg * 8];
            float4 a0 = *(const float4*)sa;
            float4 a1 = *(const float4*)(sa + 4);
            float4 b0 = *(const float4*)sb;
            float4 b1 = *(const float4*)(sb + 4);
            bf16x8 ta = { (bf16_t)a0.x, (bf16_t)a0.y, (bf16_t)a0.z, (bf16_t)a0.w,
                          (bf16_t)a1.x, (bf16_t)a1.y, (bf16_t)a1.z, (bf16_t)a1.w };
            bf16x8 tb = { (bf16_t)b0.x, (bf16_t)b0.y, (bf16_t)b0.z, (bf16_t)b0.w,
                          (bf16_t)b1.x, (bf16_t)b1.y, (bf16_t)b1.z, (bf16_t)b1.w };
            *(bf16x8*)&As[row * LDK + seg * 8] = ta;
            *(bf16x8*)&Bs[row * LDK + seg * 8] = tb;
        }
        __syncthreads();
#pragma unroll
        for (int kk = 0; kk < 64; kk += 32) {
            bf16x8 afr[4], bfr[4];
#pragma unroll
            for (int i = 0; i < 4; ++i)
                afr[i] = *(const bf16x8*)&As[(wm + i * 16 + l16) * LDK + kk + q * 8];
#pragma unroll
            for (int j = 0; j < 4; ++j)
                bfr[j] = *(const bf16x8*)&Bs[(wn + j * 16 + l16) * LDK + kk + q * 8];
#pragma unroll
            for (int i = 0; i < 4; ++i)
#pragma unroll
                for (int j = 0; j < 4; ++j)
                    acc[i][j] = __builtin_amdgcn_mfma_f32_16x16x32_bf16(
                        afr[i], bfr[j], acc[i][j], 0, 0, 0);
        }
        __syncthreads();
    }

#pragma unroll
    for (int i = 0; i < 4; ++i) {
        int grow = m0 + wm + i * 16 + q * 4;
#pragma unroll
        for (int j = 0; j < 4; ++j) {
            int gcol = n0 + wn + j * 16 + l16;
            float bia = bias[gcol];
#pragma unroll
            for (int r = 0; r < 4; ++r) {
                float v = acc[i][j][r] + bia;
                out[(size_t)(grow + r) * N1 + gcol] = (ZT)v;
            }
        }
    }
}

// ---------------------------------------------------------------------------
// Phase 2: persistent kernel. R6 = R2-proven coherence + 4-block cliques.
//  - 8 independent cliques = (2 dir) x (4 batch-row-groups of 16 rows); the
//    recurrence is row-independent, so group g's h is produced/consumed only
//    within clique g. STATIC assignment: clique = blockIdx.x & 7,
//    role = blockIdx.x >> 3 (no XCD discovery -- R5's failure mode removed;
//    &7 gives free XCD locality IF dispatch is round-robin, never required).
//  - 32 blocks x 512 threads (8 waves); wave owns 16 rows x 16 gate-cols x
//    3 gates = 48 MFMA/step (identical per-wave geometry/indexing to R2).
//    Clique = 4 blocks covering the group's 512 cols.
//  - Coherence exactly as R2 (passed, absmax 5.9e-3): h stores
//    global_store_short sc0 sc1 + vmcnt(0); h loads global_load_dwordx4
//    sc0 sc1; agent-scope counter RMW arrival (4 per step, was 32);
//    tid0-only poll, bounded spin; zi prefetch + out stores ride the poll.
//  - R4 lessons: __launch_bounds__(512) with NO min-occupancy arg (no VGPR
//    cap below the ~176-reg need); no wide polls.
// ---------------------------------------------------------------------------
template <typename ZT>
__device__ __forceinline__ float zcvt(unsigned v)
{
    if constexpr (sizeof(ZT) == 4)
        return __builtin_bit_cast(float, v);
    else
        return __builtin_bit_cast(float, v << 16);   // bf16 bits -> f32
}

template <typename ZT>
__global__ __launch_bounds__(512) void gru_persist(
    const ZT* __restrict__ zi,            // [2][M1][N1]
    const float* __restrict__ whh_fw,     // [1536][512] fp32
    const float* __restrict__ whh_bw,
    const float* __restrict__ bhh_fw,
    const float* __restrict__ bhh_bw,
    bf16_t* __restrict__ hb16,            // [8 clique][2 buf][16][512]
    float* __restrict__ out,              // [B][T][2H]
    float* __restrict__ hlast,            // [2][64][512]
    unsigned int* __restrict__ ctrl)      // per-clique counters, 256B apart
{
    const int tid  = threadIdx.x;
    const int lane = tid & 63;
    const int wave = tid >> 6;            // 0..7
    const int q    = lane >> 4;
    const int l16  = lane & 15;

    const int clique = blockIdx.x & 7;    // (dir, grp)
    const int role   = blockIdx.x >> 3;   // 0..3 : 128-col chunk
    const int dir    = clique >> 2;
    const int grp    = clique & 3;
    const int cw     = role * 128 + wave * 16;   // wave's 16 gate-cols
    const int c      = cw + l16;
    const int wmg    = grp * 16;                 // global batch-row base

    const float* __restrict__ whh = dir ? whh_bw : whh_fw;
    const float* __restrict__ bhh = dir ? bhh_bw : bhh_fw;
    const ZT* __restrict__ zid = zi + (size_t)dir * M1 * N1;
    unsigned int* cnt = ctrl + clique * 64;

    // --- persistent weights: B-frag layout B[n=l16][k=q*8+j] ---
    bf16x8 wreg[3][16];
#pragma unroll
    for (int g = 0; g < 3; ++g) {
        const float* wr = &whh[(size_t)(g * H + cw + l16) * H];
#pragma unroll
        for (int kt = 0; kt < 16; ++kt) {
            float4 a = *(const float4*)&wr[kt * 32 + q * 8];
            float4 b = *(const float4*)&wr[kt * 32 + q * 8 + 4];
            wreg[g][kt] = (bf16x8){ (bf16_t)a.x, (bf16_t)a.y, (bf16_t)a.z, (bf16_t)a.w,
                                    (bf16_t)b.x, (bf16_t)b.y, (bf16_t)b.z, (bf16_t)b.w };
        }
    }
    const float bh_r = bhh[c];
    const float bh_z = bhh[H + c];
    const float bh_n = bhh[2 * H + c];

    // clique-local h ping-pong (group-local rows 0..15)
    bf16_t* hc = hb16 + (size_t)clique * 2 * 16 * H;
    const bf16_t* rd0 = hc + (size_t)l16 * H + q * 8;
    const bf16_t* rd1 = rd0 + 16 * H;
    bf16_t* wr0 = hc + (size_t)(q * 4) * H + c;
    bf16_t* wr1 = wr0 + 16 * H;

    float hcur[4] = {0.f, 0.f, 0.f, 0.f};
    unsigned zr[3][4];

#define ISSUE_ZI(tt) do {                                                         \
    _Pragma("unroll")                                                             \
    for (int r_ = 0; r_ < 4; ++r_) {                                              \
        const ZT* zb_ = zid + ((size_t)(wmg + q * 4 + r_) * T + (size_t)(tt)) * N1\
                            + H + c;                                              \
        if constexpr (sizeof(ZT) == 4) {                                          \
            asm volatile("global_load_dword %0, %1, off offset:-2048"             \
                         : "=&v"(zr[0][r_]) : "v"(zb_) : "memory");               \
            asm volatile("global_load_dword %0, %1, off"                          \
                         : "=&v"(zr[1][r_]) : "v"(zb_) : "memory");               \
            asm volatile("global_load_dword %0, %1, off offset:2048"              \
                         : "=&v"(zr[2][r_]) : "v"(zb_) : "memory");               \
        } else {                                                                  \
            asm volatile("global_load_ushort %0, %1, off offset:-1024"            \
                         : "=&v"(zr[0][r_]) : "v"(zb_) : "memory");               \
            asm volatile("global_load_ushort %0, %1, off"                         \
                         : "=&v"(zr[1][r_]) : "v"(zb_) : "memory");               \
            asm volatile("global_load_ushort %0, %1, off offset:1024"             \
                         : "=&v"(zr[2][r_]) : "v"(zb_) : "memory");               \
        }                                                                         \
    }                                                                             \
} while (0)

    // prologue zi (drained by iter-0's vmcnt(0))
    {
        const int t0 = dir ? (T - 1) : 0;
        ISSUE_ZI(t0);
    }

#pragma unroll 1
    for (int s = 0; s < T; ++s) {
        const int t = dir ? (T - 1 - s) : s;
        const bf16_t* hrd = (s & 1) ? rd1 : rd0;
        bf16_t*       hwr = (s & 1) ? wr0 : wr1;

        // ---- coherent h loads: 16 x b128, fresh from LLC ----
        bf16x8 hf[16];
#define LDH(i, OFFSTR)                                                        \
        asm volatile("global_load_dwordx4 %0, %1, off offset:" OFFSTR         \
                     " sc0 sc1" : "=&v"(hf[i]) : "v"(hrd) : "memory");
        LDH(0,  "0")    LDH(1,  "64")   LDH(2,  "128")  LDH(3,  "192")
        LDH(4,  "256")  LDH(5,  "320")  LDH(6,  "384")  LDH(7,  "448")
        LDH(8,  "512")  LDH(9,  "576")  LDH(10, "640")  LDH(11, "704")
        LDH(12, "768")  LDH(13, "832")  LDH(14, "896")  LDH(15, "960")
#undef LDH
        __builtin_amdgcn_sched_barrier(0);
        asm volatile("s_waitcnt vmcnt(0)" ::: "memory");
        __builtin_amdgcn_sched_barrier(0);

        // ---- zh = h @ whh^T : 6 acc chains (gate x K-parity) ----
        f32x4 acc[3][2] = {};
#pragma unroll
        for (int kt = 0; kt < 16; ++kt) {
#pragma unroll
            for (int g = 0; g < 3; ++g)
                acc[g][kt & 1] = __builtin_amdgcn_mfma_f32_16x16x32_bf16(
                    hf[kt], wreg[g][kt], acc[g][kt & 1], 0, 0, 0);
        }

        // ---- gates + blend (R2-exact math); C row = q*4+r, col = l16 ----
        float hn4[4];
#pragma unroll
        for (int r = 0; r < 4; ++r) {
            float zh_r = acc[0][0][r] + acc[0][1][r] + bh_r;
            float zh_z = acc[1][0][r] + acc[1][1][r] + bh_z;
            float zh_n = acc[2][0][r] + acc[2][1][r] + bh_n;
            float zi_r = zcvt<ZT>(zr[0][r]);
            float zi_z = zcvt<ZT>(zr[1][r]);
            float zi_n = zcvt<ZT>(zr[2][r]);
            float rg = 1.f / (1.f + __expf(-(zi_r + zh_r)));
            float zg = 1.f / (1.f + __expf(-(zi_z + zh_z)));
            float ng = tanhf(zi_n + rg * zh_n);
            float hn = (1.f - zg) * ng + zg * hcur[r];
            hcur[r] = hn;
            hn4[r] = hn;
        }

        // ---- 4 coherent h-stores; drain ONLY them ----
        __builtin_amdgcn_sched_barrier(0);
#pragma unroll
        for (int r = 0; r < 4; ++r) {
            unsigned short hs = __builtin_bit_cast(unsigned short, (bf16_t)hn4[r]);
            asm volatile("global_store_short %0, %1, off sc0 sc1"
                         :: "v"(hwr + (size_t)r * H), "v"(hs) : "memory");
        }
        __builtin_amdgcn_sched_barrier(0);
        asm volatile("s_waitcnt vmcnt(0)" ::: "memory");   // h at coherence point
        __builtin_amdgcn_sched_barrier(0);

        if (s < T - 1) {
            // zi prefetch + out stores: issued now, complete during the poll
            const int tn = dir ? (T - 2 - s) : (s + 1);
            ISSUE_ZI(tn);
#pragma unroll
            for (int r = 0; r < 4; ++r) {
                const int row = wmg + q * 4 + r;
                float* optr = out + ((size_t)row * T + t) * (2 * H)
                                  + (size_t)dir * H + c;
                asm volatile("global_store_dword %0, %1, off"
                             :: "v"(optr), "v"(hn4[r]) : "memory");
            }
            __builtin_amdgcn_sched_barrier(0);
            __syncthreads();                 // all 8 waves' h drained
            if (tid == 0) {
                __hip_atomic_fetch_add(cnt, 1u, __ATOMIC_RELAXED,
                                       __HIP_MEMORY_SCOPE_AGENT);
                const unsigned tgt = 4u * (unsigned)(s + 1);
                unsigned tries = 0;
                while (__hip_atomic_load(cnt, __ATOMIC_RELAXED,
                                         __HIP_MEMORY_SCOPE_AGENT) < tgt) {
                    __builtin_amdgcn_s_sleep(1);
                    if (++tries > 1000000u) break;  // fail loud, not dead GPU
                }
            }
            __syncthreads();
        } else {
            // last step: out + hlast (plain; dispatch-end release flushes)
#pragma unroll
            for (int r = 0; r < 4; ++r) {
                const int row = wmg + q * 4 + r;
                float* optr = out + ((size_t)row * T + t) * (2 * H)
                                  + (size_t)dir * H + c;
                asm volatile("global_store_dword %0, %1, off"
                             :: "v"(optr), "v"(hn4[r]) : "memory");
                hlast[((size_t)dir * Bb + row) * H + c] = hn4[r];
            }
        }
    }
#undef ISSUE_ZI
}

// ---------------------------------------------------------------------------
extern "C" void kernel_launch(void* const* d_in, const int* in_sizes, int n_in,
                              void* d_out, int out_size, void* d_ws, size_t ws_size,
                              hipStream_t stream)
{
    const float* x       = (const float*)d_in[0];
    const float* w_ih_fw = (const float*)d_in[1];
    const float* w_hh_fw = (const float*)d_in[2];
    const float* b_ih_fw = (const float*)d_in[3];
    const float* b_hh_fw = (const float*)d_in[4];
    const float* w_ih_bw = (const float*)d_in[5];
    const float* w_hh_bw = (const float*)d_in[6];
    const float* b_ih_bw = (const float*)d_in[7];
    const float* b_hh_bw = (const float*)d_in[8];

    float* out   = (float*)d_out;
    float* hlast = out + (size_t)Bb * T * 2 * H;

    char* ws = (char*)d_ws;
    bf16_t*       hb16 = (bf16_t*)ws;                       // 262144 B
    unsigned int* ctrl = (unsigned int*)(ws + 262144);      // 2048 B counters
    void*         zi   = (void*)(ws + (1u << 20));          // 1 MiB offset

    const size_t need_f32 = (1ull << 20) + 2ull * M1 * N1 * sizeof(float);
    const bool use_f32 = (ws_size >= need_f32);

    // zero h ping-pong + clique counters (ws re-poisoned every launch)
    hipMemsetAsync(d_ws, 0, 262144 + 2048, stream);

    dim3 g1(M1 / 128, N1 / 128, 2);   // 256 x 12 x 2
    dim3 g2(32);                      // 32 blocks x 512 thr; clique = bx&7

    if (use_f32) {
        float* zif = (float*)zi;
        zi_gemm<float><<<g1, 256, 0, stream>>>(
            x, w_ih_fw, w_ih_bw, b_ih_fw, b_ih_bw, zif);
        gru_persist<float><<<g2, 512, 0, stream>>>(
            (const float*)zif, w_hh_fw, w_hh_bw, b_hh_fw, b_hh_bw,
            hb16, out, hlast, ctrl);
    } else {
        bf16_t* zib = (bf16_t*)zi;
        zi_gemm<bf16_t><<<g1, 256, 0, stream>>>(
            x, w_ih_fw, w_ih_bw, b_ih_fw, b_ih_bw, zib);
        gru_persist<bf16_t><<<g2, 512, 0, stream>>>(
            (const bf16_t*)zib, w_hh_fw, w_hh_bw, b_hh_fw, b_hh_bw,
            hb16, out, hlast, ctrl);
    }
}

// Round 7
// 2752.425 us; speedup vs baseline: 2.2828x; 2.2828x over previous
//
#include <hip/hip_runtime.h>
#include <hip/hip_bf16.h>

typedef __bf16 bf16_t;
typedef bf16_t bf16x8 __attribute__((ext_vector_type(8)));
typedef float  f32x4  __attribute__((ext_vector_type(4)));

constexpr int Bb = 64;
constexpr int T  = 512;
constexpr int D  = 512;
constexpr int H  = 512;
constexpr int M1 = Bb * T;     // 32768 rows of zi
constexpr int N1 = 3 * H;      // 1536 gate columns

#define LDK 72   // padded LDS row stride (bf16 elems)

// ---------------------------------------------------------------------------
// Phase 1: zi[dir] = x @ w_ih[dir]^T + b_ih   (fp32 in, bf16 MFMA, ZT out)
// 128x128 tile, BK=64, 4 waves each 64x64 via 16x16x32 bf16 MFMA. (unchanged)
// ---------------------------------------------------------------------------
template <typename ZT>
__global__ __launch_bounds__(256) void zi_gemm(
    const float* __restrict__ x,
    const float* __restrict__ w_fw, const float* __restrict__ w_bw,
    const float* __restrict__ b_fw, const float* __restrict__ b_bw,
    ZT* __restrict__ zi)
{
    const int dir = blockIdx.z;
    const float* __restrict__ w    = dir ? w_bw : w_fw;
    const float* __restrict__ bias = dir ? b_bw : b_fw;
    ZT* __restrict__ out = zi + (size_t)dir * M1 * N1;

    const int m0 = blockIdx.x * 128;
    const int n0 = blockIdx.y * 128;

    __shared__ bf16_t As[128 * LDK];
    __shared__ bf16_t Bs[128 * LDK];

    const int tid  = threadIdx.x;
    const int lane = tid & 63;
    const int wave = tid >> 6;
    const int wm = (wave >> 1) * 64;
    const int wn = (wave & 1) * 64;
    const int q   = lane >> 4;
    const int l16 = lane & 15;

    f32x4 acc[4][4] = {};

    for (int kt = 0; kt < D; kt += 64) {
#pragma unroll
        for (int p = 0; p < 4; ++p) {
            int idx = tid + p * 256;
            int row = idx >> 3;
            int seg = idx & 7;
            const float* sa = &x[(size_t)(m0 + row) * D + kt + seg * 8];
            const float* sb = &w[(size_t)(n0 + row) * D + kt + seg * 8];
            float4 a0 = *(const float4*)sa;
            float4 a1 = *(const float4*)(sa + 4);
            float4 b0 = *(const float4*)sb;
            float4 b1 = *(const float4*)(sb + 4);
            bf16x8 ta = { (bf16_t)a0.x, (bf16_t)a0.y, (bf16_t)a0.z, (bf16_t)a0.w,
                          (bf16_t)a1.x, (bf16_t)a1.y, (bf16_t)a1.z, (bf16_t)a1.w };
            bf16x8 tb = { (bf16_t)b0.x, (bf16_t)b0.y, (bf16_t)b0.z, (bf16_t)b0.w,
                          (bf16_t)b1.x, (bf16_t)b1.y, (bf16_t)b1.z, (bf16_t)b1.w };
            *(bf16x8*)&As[row * LDK + seg * 8] = ta;
            *(bf16x8*)&Bs[row * LDK + seg * 8] = tb;
        }
        __syncthreads();
#pragma unroll
        for (int kk = 0; kk < 64; kk += 32) {
            bf16x8 afr[4], bfr[4];
#pragma unroll
            for (int i = 0; i < 4; ++i)
                afr[i] = *(const bf16x8*)&As[(wm + i * 16 + l16) * LDK + kk + q * 8];
#pragma unroll
            for (int j = 0; j < 4; ++j)
                bfr[j] = *(const bf16x8*)&Bs[(wn + j * 16 + l16) * LDK + kk + q * 8];
#pragma unroll
            for (int i = 0; i < 4; ++i)
#pragma unroll
                for (int j = 0; j < 4; ++j)
                    acc[i][j] = __builtin_amdgcn_mfma_f32_16x16x32_bf16(
                        afr[i], bfr[j], acc[i][j], 0, 0, 0);
        }
        __syncthreads();
    }

#pragma unroll
    for (int i = 0; i < 4; ++i) {
        int grow = m0 + wm + i * 16 + q * 4;
#pragma unroll
        for (int j = 0; j < 4; ++j) {
            int gcol = n0 + wn + j * 16 + l16;
            float bia = bias[gcol];
#pragma unroll
            for (int r = 0; r < 4; ++r) {
                float v = acc[i][j][r] + bia;
                out[(size_t)(grow + r) * N1 + gcol] = (ZT)v;
            }
        }
    }
}

// ---------------------------------------------------------------------------
// Phase 2: persistent kernel. R7 = clique decomposition at the PROVEN shape.
//  - R6 proved the clique geometry correct (absmax 5.9e-3) but was poisoned
//    by 512-thr blocks -> VGPR capped at 128 -> scratch spills (R4 same).
//    R7 reruns it at R2's proven shape: 256 thr, __launch_bounds__(256,1)
//    -> ~176 VGPR, no spill.
//  - 64 blocks x 4 waves. clique = blockIdx.x & 7 = (dir, batch-row-group);
//    role = blockIdx.x >> 3 (0..7) = 64-col chunk. Wave owns 16 rows x
//    16 gate-cols x 3 gates = 48 MFMA/step (bit-identical per-wave code).
//  - Barrier: 8 arrivals/clique/step (was 32 in R2), counters on separate
//    256B lines -> contention partitioned 8 ways. tid0-only RMW + poll,
//    bounded spin. Coherence exactly R2's: h stores sc0 sc1 + vmcnt(0);
//    h loads sc0 sc1; zi prefetch + out stores ride the poll window.
// ---------------------------------------------------------------------------
template <typename ZT>
__device__ __forceinline__ float zcvt(unsigned v)
{
    if constexpr (sizeof(ZT) == 4)
        return __builtin_bit_cast(float, v);
    else
        return __builtin_bit_cast(float, v << 16);   // bf16 bits -> f32
}

template <typename ZT>
__global__ __launch_bounds__(256, 1) void gru_persist(
    const ZT* __restrict__ zi,            // [2][M1][N1]
    const float* __restrict__ whh_fw,     // [1536][512] fp32
    const float* __restrict__ whh_bw,
    const float* __restrict__ bhh_fw,
    const float* __restrict__ bhh_bw,
    bf16_t* __restrict__ hb16,            // [8 clique][2 buf][16][512]
    float* __restrict__ out,              // [B][T][2H]
    float* __restrict__ hlast,            // [2][64][512]
    unsigned int* __restrict__ ctrl)      // per-clique counters, 256B apart
{
    const int tid  = threadIdx.x;
    const int lane = tid & 63;
    const int wave = tid >> 6;            // 0..3
    const int q    = lane >> 4;
    const int l16  = lane & 15;

    const int clique = blockIdx.x & 7;    // (dir, grp)
    const int role   = blockIdx.x >> 3;   // 0..7 : 64-col chunk
    const int dir    = clique >> 2;
    const int grp    = clique & 3;
    const int cw     = role * 64 + wave * 16;    // wave's 16 gate-cols
    const int c      = cw + l16;
    const int wmg    = grp * 16;                 // global batch-row base

    const float* __restrict__ whh = dir ? whh_bw : whh_fw;
    const float* __restrict__ bhh = dir ? bhh_bw : bhh_fw;
    const ZT* __restrict__ zid = zi + (size_t)dir * M1 * N1;
    unsigned int* cnt = ctrl + clique * 64;

    // --- persistent weights: B-frag layout B[n=l16][k=q*8+j] ---
    bf16x8 wreg[3][16];
#pragma unroll
    for (int g = 0; g < 3; ++g) {
        const float* wr = &whh[(size_t)(g * H + cw + l16) * H];
#pragma unroll
        for (int kt = 0; kt < 16; ++kt) {
            float4 a = *(const float4*)&wr[kt * 32 + q * 8];
            float4 b = *(const float4*)&wr[kt * 32 + q * 8 + 4];
            wreg[g][kt] = (bf16x8){ (bf16_t)a.x, (bf16_t)a.y, (bf16_t)a.z, (bf16_t)a.w,
                                    (bf16_t)b.x, (bf16_t)b.y, (bf16_t)b.z, (bf16_t)b.w };
        }
    }
    const float bh_r = bhh[c];
    const float bh_z = bhh[H + c];
    const float bh_n = bhh[2 * H + c];

    // clique-local h ping-pong (group-local rows 0..15)
    bf16_t* hc = hb16 + (size_t)clique * 2 * 16 * H;
    const bf16_t* rd0 = hc + (size_t)l16 * H + q * 8;
    const bf16_t* rd1 = rd0 + 16 * H;
    bf16_t* wr0 = hc + (size_t)(q * 4) * H + c;
    bf16_t* wr1 = wr0 + 16 * H;

    float hcur[4] = {0.f, 0.f, 0.f, 0.f};
    unsigned zr[3][4];

#define ISSUE_ZI(tt) do {                                                         \
    _Pragma("unroll")                                                             \
    for (int r_ = 0; r_ < 4; ++r_) {                                              \
        const ZT* zb_ = zid + ((size_t)(wmg + q * 4 + r_) * T + (size_t)(tt)) * N1\
                            + H + c;                                              \
        if constexpr (sizeof(ZT) == 4) {                                          \
            asm volatile("global_load_dword %0, %1, off offset:-2048"             \
                         : "=&v"(zr[0][r_]) : "v"(zb_) : "memory");               \
            asm volatile("global_load_dword %0, %1, off"                          \
                         : "=&v"(zr[1][r_]) : "v"(zb_) : "memory");               \
            asm volatile("global_load_dword %0, %1, off offset:2048"              \
                         : "=&v"(zr[2][r_]) : "v"(zb_) : "memory");               \
        } else {                                                                  \
            asm volatile("global_load_ushort %0, %1, off offset:-1024"            \
                         : "=&v"(zr[0][r_]) : "v"(zb_) : "memory");               \
            asm volatile("global_load_ushort %0, %1, off"                          \
                         : "=&v"(zr[1][r_]) : "v"(zb_) : "memory");               \
            asm volatile("global_load_ushort %0, %1, off offset:1024"             \
                         : "=&v"(zr[2][r_]) : "v"(zb_) : "memory");               \
        }                                                                         \
    }                                                                             \
} while (0)

    // prologue zi (drained by iter-0's vmcnt(0))
    {
        const int t0 = dir ? (T - 1) : 0;
        ISSUE_ZI(t0);
    }

#pragma unroll 1
    for (int s = 0; s < T; ++s) {
        const int t = dir ? (T - 1 - s) : s;
        const bf16_t* hrd = (s & 1) ? rd1 : rd0;
        bf16_t*       hwr = (s & 1) ? wr0 : wr1;

        // ---- coherent h loads: 16 x b128, fresh from LLC ----
        bf16x8 hf[16];
#define LDH(i, OFFSTR)                                                        \
        asm volatile("global_load_dwordx4 %0, %1, off offset:" OFFSTR         \
                     " sc0 sc1" : "=&v"(hf[i]) : "v"(hrd) : "memory");
        LDH(0,  "0")    LDH(1,  "64")   LDH(2,  "128")  LDH(3,  "192")
        LDH(4,  "256")  LDH(5,  "320")  LDH(6,  "384")  LDH(7,  "448")
        LDH(8,  "512")  LDH(9,  "576")  LDH(10, "640")  LDH(11, "704")
        LDH(12, "768")  LDH(13, "832")  LDH(14, "896")  LDH(15, "960")
#undef LDH
        __builtin_amdgcn_sched_barrier(0);
        asm volatile("s_waitcnt vmcnt(0)" ::: "memory");
        __builtin_amdgcn_sched_barrier(0);

        // ---- zh = h @ whh^T : 6 acc chains (gate x K-parity) ----
        f32x4 acc[3][2] = {};
#pragma unroll
        for (int kt = 0; kt < 16; ++kt) {
#pragma unroll
            for (int g = 0; g < 3; ++g)
                acc[g][kt & 1] = __builtin_amdgcn_mfma_f32_16x16x32_bf16(
                    hf[kt], wreg[g][kt], acc[g][kt & 1], 0, 0, 0);
        }

        // ---- gates + blend (R2-exact math); C row = q*4+r, col = l16 ----
        float hn4[4];
#pragma unroll
        for (int r = 0; r < 4; ++r) {
            float zh_r = acc[0][0][r] + acc[0][1][r] + bh_r;
            float zh_z = acc[1][0][r] + acc[1][1][r] + bh_z;
            float zh_n = acc[2][0][r] + acc[2][1][r] + bh_n;
            float zi_r = zcvt<ZT>(zr[0][r]);
            float zi_z = zcvt<ZT>(zr[1][r]);
            float zi_n = zcvt<ZT>(zr[2][r]);
            float rg = 1.f / (1.f + __expf(-(zi_r + zh_r)));
            float zg = 1.f / (1.f + __expf(-(zi_z + zh_z)));
            float ng = tanhf(zi_n + rg * zh_n);
            float hn = (1.f - zg) * ng + zg * hcur[r];
            hcur[r] = hn;
            hn4[r] = hn;
        }

        // ---- 4 coherent h-stores; drain ONLY them ----
        __builtin_amdgcn_sched_barrier(0);
#pragma unroll
        for (int r = 0; r < 4; ++r) {
            unsigned short hs = __builtin_bit_cast(unsigned short, (bf16_t)hn4[r]);
            asm volatile("global_store_short %0, %1, off sc0 sc1"
                         :: "v"(hwr + (size_t)r * H), "v"(hs) : "memory");
        }
        __builtin_amdgcn_sched_barrier(0);
        asm volatile("s_waitcnt vmcnt(0)" ::: "memory");   // h at coherence point
        __builtin_amdgcn_sched_barrier(0);

        if (s < T - 1) {
            // zi prefetch + out stores: issued now, complete during the poll
            const int tn = dir ? (T - 2 - s) : (s + 1);
            ISSUE_ZI(tn);
#pragma unroll
            for (int r = 0; r < 4; ++r) {
                const int row = wmg + q * 4 + r;
                float* optr = out + ((size_t)row * T + t) * (2 * H)
                                  + (size_t)dir * H + c;
                asm volatile("global_store_dword %0, %1, off"
                             :: "v"(optr), "v"(hn4[r]) : "memory");
            }
            __builtin_amdgcn_sched_barrier(0);
            __syncthreads();                 // all 4 waves' h drained
            if (tid == 0) {
                __hip_atomic_fetch_add(cnt, 1u, __ATOMIC_RELAXED,
                                       __HIP_MEMORY_SCOPE_AGENT);
                const unsigned tgt = 8u * (unsigned)(s + 1);
                unsigned tries = 0;
                while (__hip_atomic_load(cnt, __ATOMIC_RELAXED,
                                         __HIP_MEMORY_SCOPE_AGENT) < tgt) {
                    __builtin_amdgcn_s_sleep(1);
                    if (++tries > 1000000u) break;  // fail loud, not dead GPU
                }
            }
            __syncthreads();
        } else {
            // last step: out + hlast (plain; dispatch-end release flushes)
#pragma unroll
            for (int r = 0; r < 4; ++r) {
                const int row = wmg + q * 4 + r;
                float* optr = out + ((size_t)row * T + t) * (2 * H)
                                  + (size_t)dir * H + c;
                asm volatile("global_store_dword %0, %1, off"
                             :: "v"(optr), "v"(hn4[r]) : "memory");
                hlast[((size_t)dir * Bb + row) * H + c] = hn4[r];
            }
        }
    }
#undef ISSUE_ZI
}

// ---------------------------------------------------------------------------
extern "C" void kernel_launch(void* const* d_in, const int* in_sizes, int n_in,
                              void* d_out, int out_size, void* d_ws, size_t ws_size,
                              hipStream_t stream)
{
    const float* x       = (const float*)d_in[0];
    const float* w_ih_fw = (const float*)d_in[1];
    const float* w_hh_fw = (const float*)d_in[2];
    const float* b_ih_fw = (const float*)d_in[3];
    const float* b_hh_fw = (const float*)d_in[4];
    const float* w_ih_bw = (const float*)d_in[5];
    const float* w_hh_bw = (const float*)d_in[6];
    const float* b_ih_bw = (const float*)d_in[7];
    const float* b_hh_bw = (const float*)d_in[8];

    float* out   = (float*)d_out;
    float* hlast = out + (size_t)Bb * T * 2 * H;

    char* ws = (char*)d_ws;
    bf16_t*       hb16 = (bf16_t*)ws;                       // 262144 B
    unsigned int* ctrl = (unsigned int*)(ws + 262144);      // 2048 B counters
    void*         zi   = (void*)(ws + (1u << 20));          // 1 MiB offset

    const size_t need_f32 = (1ull << 20) + 2ull * M1 * N1 * sizeof(float);
    const bool use_f32 = (ws_size >= need_f32);

    // zero h ping-pong + clique counters (ws re-poisoned every launch)
    hipMemsetAsync(d_ws, 0, 262144 + 2048, stream);

    dim3 g1(M1 / 128, N1 / 128, 2);   // 256 x 12 x 2
    dim3 g2(64);                      // 64 blocks x 256 thr; clique = bx&7

    if (use_f32) {
        float* zif = (float*)zi;
        zi_gemm<float><<<g1, 256, 0, stream>>>(
            x, w_ih_fw, w_ih_bw, b_ih_fw, b_ih_bw, zif);
        gru_persist<float><<<g2, 256, 0, stream>>>(
            (const float*)zif, w_hh_fw, w_hh_bw, b_hh_fw, b_hh_bw,
            hb16, out, hlast, ctrl);
    } else {
        bf16_t* zib = (bf16_t*)zi;
        zi_gemm<bf16_t><<<g1, 256, 0, stream>>>(
            x, w_ih_fw, w_ih_bw, b_ih_fw, b_ih_bw, zib);
        gru_persist<bf16_t><<<g2, 256, 0, stream>>>(
            (const bf16_t*)zib, w_hh_fw, w_hh_bw, b_hh_fw, b_hh_bw,
            hb16, out, hlast, ctrl);
    }
}